// Round 7
// baseline (121.801 us; speedup 1.0000x reference)
//
#include <hip/hip_runtime.h>
#include <math.h>

#define HID 128
#define TPB 1024  // 16 waves; 1 block/CU (135.5KB LDS) -> 4 waves/SIMD, VGPR cap 128
#define NW  16    // waves per block
#define GRIDB 256 // 1 block per CU

typedef __bf16 bf16;
typedef bf16 bf16x8 __attribute__((ext_vector_type(8)));
typedef bf16 bf16x4 __attribute__((ext_vector_type(4)));
typedef float floatx4 __attribute__((ext_vector_type(4)));

// rcp-based tanh; packed f32 for everything but the trans ops.
__device__ __forceinline__ floatx4 tanh4(floatx4 z) {
    floatx4 t = z * 2.885390081777927f;                  // exp(2x) via exp2
    floatx4 e = { __builtin_amdgcn_exp2f(t[0]), __builtin_amdgcn_exp2f(t[1]),
                  __builtin_amdgcn_exp2f(t[2]), __builtin_amdgcn_exp2f(t[3]) };
    e = e + 1.0f;
    floatx4 r = { __builtin_amdgcn_rcpf(e[0]), __builtin_amdgcn_rcpf(e[1]),
                  __builtin_amdgcn_rcpf(e[2]), __builtin_amdgcn_rcpf(e[3]) };
    return 1.0f - 2.0f * r;
}

// WAVE-AUTONOMOUS + SKEWED-PIPELINE formulation (r6 post-mortem: kernel ~27us
// vs ~12us pipe-sum => exposed dependency latency; this round: batch the two
// C->B transforms into single-wait round trips, drop the myH buffer entirely,
// and overlap tile t+1's tanh block (P1) under tile t's GEMM2/phase5).
//
// MFMA 16x16x32 layouts:
//   A-frag: lane holds A[m=lane&15][k=(lane>>4)*8+idx]
//   B-frag: lane holds B[k=(lane>>4)*8+idx][n=lane&15]
//   C/D:    lane/reg holds D[row=(lane>>4)*4+reg][col=lane&15]
// Sample ALWAYS = lane&15. P1 produces H1^T B-frags directly in regs (breg).
// GEMM1t: Z2^T = W2^T @ H1^T (A=sW2A lines, B=breg)
// GEMM2t: S^T  = W2 @ G2^T   (A=sW2R lines, B via batched transform in sXf)
// GEMM3t: dV^T = W1 @ G1^T   (A=sW1A lines, B = (1-breg^2)*transform(acc2))
//
// C->B transform (proven index algebra): C-tile jt, lane(lq,lrow), reg r holds
// k_global = 16*jt+4*lq+r of column lrow. Per 32-k line L=jt>>1:
//   unswizzled block = k_local>>3 = 2*(jt&1)+(lq>>1); offset = 4*(lq&1)+r.
// Line layout [16 samples][32 k] bf16 (1KB/line, 4 lines = 4KB/wave in sXf).
// XOR swizzle: block ^= (lrow&3) on BOTH write and read (bijective within the
// 64B sample row; spreads the 8-way b64-write bank conflict to ~4-way).
// Read side: lane(lq,lrow) reads k_local = 8*lq..+7 = block lq^(lrow&3), b128.
// Phase5 reuses the SAME transform on acc2 (S^T has identical C layout); the
// (1-h1^2) factor applies post-transform from breg (h1 already B-frag layout;
// bf16 h1 = identical rounding to the old myH path).

__global__ __launch_bounds__(TPB, 4)
void lnn_kernel(const float* __restrict__ X,
                const float* __restrict__ W1,
                const float* __restrict__ b1,
                const float* __restrict__ b2,
                const float* __restrict__ W3,
                const float* __restrict__ W2,
                float* __restrict__ out,
                int B, int nchunk)
{
    // 32KB: W2^T A-frags [(jt*4+kt)*64+lane]*8 : lane(q,lr) = W2[32kt+8q+idx][16jt+lr]
    __shared__ __align__(16) bf16 sW2A[16384];
    // 32KB: W2 row A-frags [(it*4+jt2)*64+lane]*8 : lane(q,lr) = W2[16it+lr][32jt2+8q+idx]
    __shared__ __align__(16) bf16 sW2R[16384];
    // 64KB: per-wave transform scratch, 4 lines x [16 samples][32 k] bf16
    __shared__ __align__(16) bf16 sXf[NW][2048];
    // 4KB: W1 A-frag lines for GEMM3 (rows>=4 zero)
    __shared__ __align__(16) bf16 sW1A[4][512];
    __shared__ __align__(16) float sW1r[4][HID]; // W1 row-major (for P1)
    __shared__ __align__(16) float sB1[HID], sB2[HID], sW3[HID];

    const int tid  = threadIdx.x;
    const int w    = tid >> 6;
    const int lane = tid & 63;
    const int lrow = lane & 15;
    const int lq   = lane >> 4;
    const int swz  = lrow & 3;

    // ---------------- one-time staging ----------------
    if (tid < 512) { int r = tid >> 7, j = tid & (HID - 1); sW1r[r][j] = W1[r * HID + j]; }
    if (tid < HID) sB1[tid] = b1[tid];
    else if (tid < 2 * HID) sB2[tid - HID] = b2[tid - HID];
    else if (tid < 3 * HID) sW3[tid - 2 * HID] = W3[tid - 2 * HID];

    #pragma unroll
    for (int tt = 0; tt < 2; ++tt) {
        int e = tid + tt * TPB;       // 0..2047 frag-line slots
        int t = e >> 6, l = e & 63;
        int a = t >> 2, bidx = t & 3; // (jt,kt) for sW2A ; (it,jt2) for sW2R
        int lr = l & 15, q = l >> 4;
        bf16x8 f;
        #pragma unroll
        for (int idx = 0; idx < 8; ++idx)
            f[idx] = (bf16)W2[(32*bidx + 8*q + idx) * HID + 16*a + lr];
        *reinterpret_cast<bf16x8*>(&sW2A[e * 8]) = f;
        const float4* rp = reinterpret_cast<const float4*>(&W2[(16*a + lr) * HID + 32*bidx + 8*q]);
        float4 r0 = rp[0], r1 = rp[1];
        bf16x8 g;
        g[0]=(bf16)r0.x; g[1]=(bf16)r0.y; g[2]=(bf16)r0.z; g[3]=(bf16)r0.w;
        g[4]=(bf16)r1.x; g[5]=(bf16)r1.y; g[6]=(bf16)r1.z; g[7]=(bf16)r1.w;
        *reinterpret_cast<bf16x8*>(&sW2R[e * 8]) = g;
    }
    if (tid < 256) { // W1 A-frag lines: A[m=lr][k=32m+8q+idx], rows>=4 zero
        int m = tid >> 6, l = tid & 63;
        int lr = l & 15, q = l >> 4;
        bf16x8 f = {};
        if (lr < 4) {
            #pragma unroll
            for (int idx = 0; idx < 8; ++idx)
                f[idx] = (bf16)W1[lr * HID + 32*m + 8*q + idx];
        }
        *reinterpret_cast<bf16x8*>(&sW1A[m][l * 8]) = f;
    }
    __syncthreads(); // ONLY barrier in the kernel

    bf16* const myX = &sXf[w][0];

    // P1: feat -> H1^T B-frags in regs (dst[kt] holds h1[32kt+8lq+idx][lrow])
    auto P1 = [&](float f0, float f1, float f2, float f3, bf16x8* dst) {
        #pragma unroll
        for (int kt = 0; kt < 4; ++kt) {
            int jb = 32 * kt + 8 * lq;
            floatx4 w0a = *reinterpret_cast<const floatx4*>(&sW1r[0][jb]);
            floatx4 w0b = *reinterpret_cast<const floatx4*>(&sW1r[0][jb+4]);
            floatx4 w1a = *reinterpret_cast<const floatx4*>(&sW1r[1][jb]);
            floatx4 w1b = *reinterpret_cast<const floatx4*>(&sW1r[1][jb+4]);
            floatx4 w2a = *reinterpret_cast<const floatx4*>(&sW1r[2][jb]);
            floatx4 w2b = *reinterpret_cast<const floatx4*>(&sW1r[2][jb+4]);
            floatx4 w3a = *reinterpret_cast<const floatx4*>(&sW1r[3][jb]);
            floatx4 w3b = *reinterpret_cast<const floatx4*>(&sW1r[3][jb+4]);
            floatx4 bba = *reinterpret_cast<const floatx4*>(&sB1[jb]);
            floatx4 bbb = *reinterpret_cast<const floatx4*>(&sB1[jb+4]);
            floatx4 za = bba + f0*w0a + f1*w1a + f2*w2a + f3*w3a;
            floatx4 zb = bbb + f0*w0b + f1*w1b + f2*w2b + f3*w3b;
            floatx4 ha = tanh4(za);
            floatx4 hb = tanh4(zb);
            bf16x8 hf;
            hf[0]=(bf16)ha[0]; hf[1]=(bf16)ha[1]; hf[2]=(bf16)ha[2]; hf[3]=(bf16)ha[3];
            hf[4]=(bf16)hb[0]; hf[5]=(bf16)hb[1]; hf[6]=(bf16)hb[2]; hf[7]=(bf16)hb[3];
            dst[kt] = hf;
        }
    };
    auto loadX = [&](int t) -> float4 {
        int gc = t * 16 + lrow; gc = gc < B ? gc : (B - 1);
        return reinterpret_cast<const float4*>(X)[gc];
    };

    const int tileStride = GRIDB * NW;
    const int t0 = (int)blockIdx.x * NW + w;
    const floatx4 fz = floatx4{0.f,0.f,0.f,0.f};

    // pipeline prologue: tile t0's state + P1
    float4 xc = loadX(t0);
    float s1c, c1c, s2c, c2c;
    __sincosf(xc.x, &s1c, &c1c);
    __sincosf(xc.y, &s2c, &c2c);
    float qd1 = xc.z, qd2 = xc.w;
    bf16x8 bregc[4];
    P1(s1c, c1c, s2c, c2c, bregc);

    #pragma unroll 1
    for (int c = 0; c < nchunk; ++c) {
        const int tile = t0 + c * tileStride;
        if (tile * 16 >= B) break;              // per-wave divergence OK: no barriers
        const int S0 = tile * 16;
        float4 xn = loadX(tile + tileStride);   // clamped; garbage-safe on last iter

        // ---- GEMM1t: Z2^T = W2^T @ H1^T ----
        floatx4 acc[8];
        #pragma unroll
        for (int jt = 0; jt < 8; ++jt) {
            acc[jt] = __builtin_amdgcn_mfma_f32_16x16x32_bf16(
                *reinterpret_cast<const bf16x8*>(&sW2A[((jt*4 + 0)*64 + lane)*8]),
                bregc[0], fz, 0,0,0);
            #pragma unroll
            for (int kt = 1; kt < 4; ++kt)
                acc[jt] = __builtin_amdgcn_mfma_f32_16x16x32_bf16(
                    *reinterpret_cast<const bf16x8*>(&sW2A[((jt*4 + kt)*64 + lane)*8]),
                    bregc[kt], acc[jt], 0,0,0);
        }

        // ---- Phase 3a: G2 = (1-tanh^2(Z2+b2))*W3, batched transform writes ----
        #pragma unroll
        for (int jt = 0; jt < 8; ++jt) {
            int jb = 16*jt + 4*lq;
            floatx4 b2v = *reinterpret_cast<const floatx4*>(&sB2[jb]);
            floatx4 w3v = *reinterpret_cast<const floatx4*>(&sW3[jb]);
            floatx4 h = tanh4(acc[jt] + b2v);
            floatx4 gv = (1.0f - h*h) * w3v;
            bf16x4 g;
            g[0]=(bf16)gv[0]; g[1]=(bf16)gv[1]; g[2]=(bf16)gv[2]; g[3]=(bf16)gv[3];
            int blk = (2*(jt&1) + (lq>>1)) ^ swz;
            *reinterpret_cast<bf16x4*>(&myX[(jt>>1)*512 + lrow*32 + blk*8 + 4*(lq&1)]) = g;
        }
        // ---- Phase 3b + GEMM2t: single wait, 4 B-line reads, 32 MFMA ----
        bf16x8 gB[4];
        #pragma unroll
        for (int L = 0; L < 4; ++L)
            gB[L] = *reinterpret_cast<const bf16x8*>(&myX[L*512 + lrow*32 + (L==L ? ((lq ^ swz)*8) : 0)]);
        floatx4 acc2[8];
        #pragma unroll
        for (int it = 0; it < 8; ++it)
            acc2[it] = __builtin_amdgcn_mfma_f32_16x16x32_bf16(
                *reinterpret_cast<const bf16x8*>(&sW2R[((it*4 + 0)*64 + lane)*8]),
                gB[0], fz, 0,0,0);
        #pragma unroll
        for (int jt2 = 1; jt2 < 4; ++jt2)
            #pragma unroll
            for (int it = 0; it < 8; ++it)
                acc2[it] = __builtin_amdgcn_mfma_f32_16x16x32_bf16(
                    *reinterpret_cast<const bf16x8*>(&sW2R[((it*4 + jt2)*64 + lane)*8]),
                    gB[jt2], acc2[it], 0,0,0);

        // ---- P1 for NEXT tile (independent: scheduler overlaps with GEMM2/phase5) ----
        float s1n, c1n, s2n, c2n;
        __sincosf(xn.x, &s1n, &c1n);
        __sincosf(xn.y, &s2n, &c2n);
        bf16x8 bregn[4];
        P1(s1n, c1n, s2n, c2n, bregn);

        // ---- Phase 5a: S^T batched transform writes (same formulas, input acc2) ----
        // (in-order DS per wave: these writes cannot pass the gB reads above)
        #pragma unroll
        for (int it = 0; it < 8; ++it) {
            bf16x4 g;
            g[0]=(bf16)acc2[it][0]; g[1]=(bf16)acc2[it][1];
            g[2]=(bf16)acc2[it][2]; g[3]=(bf16)acc2[it][3];
            int blk = (2*(it&1) + (lq>>1)) ^ swz;
            *reinterpret_cast<bf16x4*>(&myX[(it>>1)*512 + lrow*32 + blk*8 + 4*(lq&1)]) = g;
        }
        // ---- Phase 5b + GEMM3t: G1 = (1-h1^2)*S from breg (B-layout match) ----
        floatx4 dv = fz;
        #pragma unroll
        for (int m = 0; m < 4; ++m) {
            bf16x8 sv = *reinterpret_cast<const bf16x8*>(&myX[m*512 + lrow*32 + (lq ^ swz)*8]);
            bf16x8 g1;
            #pragma unroll
            for (int idx = 0; idx < 8; ++idx) {
                float h = (float)bregc[m][idx];
                float s = (float)sv[idx];
                g1[idx] = (bf16)(s - s*h*h);
            }
            dv = __builtin_amdgcn_mfma_f32_16x16x32_bf16(
                *reinterpret_cast<const bf16x8*>(&sW1A[m][lane*8]), g1, dv, 0,0,0);
        }

        // ---- Epilogue: lanes 0..15 (lq=0) hold dv rows 0..3 for sample lrow ----
        if (lane < 16 && S0 + lane < B) {
            float dV0 = dv[0], dV1 = dv[1], dV2 = dv[2], dV3 = dv[3];
            float cosD = c1c * c2c + s1c * s2c;
            float sinD = s1c * c2c - c1c * s2c;
            float dVt1 = dV0 * c1c - dV1 * s1c;   // dV/dt1
            float dVt2 = dV2 * c2c - dV3 * s2c;   // dV/dt2
            float sT = qd1 * qd2 * sinD;          // dT/dt1 = -sT, dT/dt2 = +sT
            float cw = sinD * (qd2 - qd1);
            float rhs1 = (-sT - dVt1) - qd2 * cw;
            float rhs2 = ( sT - dVt2) - qd1 * cw;
            float det = 2.0f - cosD * cosD;       // det(M) in [1,2]
            float inv = __builtin_amdgcn_rcpf(det);
            float qdd1 = (rhs1 - cosD * rhs2) * inv;
            float qdd2 = (2.0f * rhs2 - cosD * rhs1) * inv;
            *reinterpret_cast<float4*>(&out[4 * (S0 + lane)]) = make_float4(qd1, qd2, qdd1, qdd2);
        }

        // rotate pipeline state
        bregc[0]=bregn[0]; bregc[1]=bregn[1]; bregc[2]=bregn[2]; bregc[3]=bregn[3];
        s1c=s1n; c1c=c1n; s2c=s2n; c2c=c2n; qd1=xn.z; qd2=xn.w;
    }
}

extern "C" void kernel_launch(void* const* d_in, const int* in_sizes, int n_in,
                              void* d_out, int out_size, void* d_ws, size_t ws_size,
                              hipStream_t stream) {
    const float* X  = (const float*)d_in[0];
    const float* W1 = (const float*)d_in[1];
    const float* b1 = (const float*)d_in[2];
    const float* W2 = (const float*)d_in[3];
    const float* b2 = (const float*)d_in[4];
    const float* W3 = (const float*)d_in[5];
    // d_in[6] = b3: constant offset on V, vanishes in all gradients
    float* out = (float*)d_out;
    int B = in_sizes[0] / 4;
    int tiles = (B + 15) >> 4;
    int nchunk = (tiles + GRIDB * NW - 1) / (GRIDB * NW);
    lnn_kernel<<<GRIDB, TPB, 0, stream>>>(X, W1, b1, b2, W3, W2, out, B, nchunk);
}

// Round 8
// 91.545 us; speedup vs baseline: 1.3305x; 1.3305x over previous
//
#include <hip/hip_runtime.h>
#include <math.h>

#define HID 128
#define TPB 1024  // 16 waves; LDS 135.5KB forces 1 block/CU -> 4 waves/SIMD
#define NW  16    // waves per block
#define GRIDB 256 // 1 block per CU

typedef __bf16 bf16;
typedef bf16 bf16x8 __attribute__((ext_vector_type(8)));
typedef bf16 bf16x4 __attribute__((ext_vector_type(4)));
typedef float floatx4 __attribute__((ext_vector_type(4)));

// rcp-based tanh; packed f32 for everything but the trans ops.
__device__ __forceinline__ floatx4 tanh4(floatx4 z) {
    floatx4 t = z * 2.885390081777927f;                  // exp(2x) via exp2
    floatx4 e = { __builtin_amdgcn_exp2f(t[0]), __builtin_amdgcn_exp2f(t[1]),
                  __builtin_amdgcn_exp2f(t[2]), __builtin_amdgcn_exp2f(t[3]) };
    e = e + 1.0f;
    floatx4 r = { __builtin_amdgcn_rcpf(e[0]), __builtin_amdgcn_rcpf(e[1]),
                  __builtin_amdgcn_rcpf(e[2]), __builtin_amdgcn_rcpf(e[3]) };
    return 1.0f - 2.0f * r;
}

// WAVE-AUTONOMOUS formulation, batched C->B transforms, ROLLING accumulators.
// r7 post-mortem: __launch_bounds__(1024,4) => 64-VGPR cap on this toolchain
// (2nd arg behaves like CUDA min-blocks: infeasible 4 blocks -> 2 blocks/CU ->
// 8 waves/SIMD -> 512/8=64) + P1-skew raised live set to ~140 => 250MB scratch
// traffic, spill-bound at 65us. THIS round: launch_bounds(1024,1) (=128 cap,
// LDS already caps real occupancy at 1 block/CU), no skew, and per-tile GEMM
// chains restructured so only ONE rolling floatx4 acc is live (was 8+8).
// REGISTER BUDGET: breg(16)+gB(16)+rolling acc(4)+temps ~= 80 < 128.
//
// MFMA 16x16x32 layouts:
//   A-frag: lane holds A[m=lane&15][k=(lane>>4)*8+idx]
//   B-frag: lane holds B[k=(lane>>4)*8+idx][n=lane&15]
//   C/D:    lane/reg holds D[row=(lane>>4)*4+reg][col=lane&15]
// Sample ALWAYS = lane&15. P1 produces H1^T B-frags directly in regs (breg).
// GEMM1t: Z2^T = W2^T @ H1^T (A=sW2A lines, B=breg)
// GEMM2t: S^T  = W2 @ G2^T   (A=sW2R lines, B via batched transform in sXf)
// GEMM3t: dV^T = W1 @ G1^T   (A=sW1A lines, B = (1-breg^2)*transform(acc2))
//
// C->B transform (algebra verified on-HW r7, absmax unchanged): C-tile jt,
// lane(lq,lrow), reg r holds k_global=16jt+4lq+r of column lrow. Line L=jt>>1:
//   block = 2*(jt&1)+(lq>>1), offset = 4*(lq&1)+r, layout [16 samp][32 k].
// XOR swizzle block^=(lrow&3) on write AND read (bijective per sample row,
// spreads 8-way b64-write conflict to ~4-way). Read: lane(lq,lrow) b128-reads
// block lq^(lrow&3). DS ops are in-order per wave => write->read needs no
// barrier; reads/writes alias myX so compiler orders them.

__global__ __launch_bounds__(TPB, 1)
void lnn_kernel(const float* __restrict__ X,
                const float* __restrict__ W1,
                const float* __restrict__ b1,
                const float* __restrict__ b2,
                const float* __restrict__ W3,
                const float* __restrict__ W2,
                float* __restrict__ out,
                int B, int nchunk)
{
    // 32KB: W2^T A-frags [(jt*4+kt)*64+lane]*8 : lane(q,lr) = W2[32kt+8q+idx][16jt+lr]
    __shared__ __align__(16) bf16 sW2A[16384];
    // 32KB: W2 row A-frags [(it*4+jt2)*64+lane]*8 : lane(q,lr) = W2[16it+lr][32jt2+8q+idx]
    __shared__ __align__(16) bf16 sW2R[16384];
    // 64KB: per-wave transform scratch, 4 lines x [16 samples][32 k] bf16
    __shared__ __align__(16) bf16 sXf[NW][2048];
    // 4KB: W1 A-frag lines for GEMM3 (rows>=4 zero)
    __shared__ __align__(16) bf16 sW1A[4][512];
    __shared__ __align__(16) float sW1r[4][HID]; // W1 row-major (for P1)
    __shared__ __align__(16) float sB1[HID], sB2[HID], sW3[HID];

    const int tid  = threadIdx.x;
    const int w    = tid >> 6;
    const int lane = tid & 63;
    const int lrow = lane & 15;
    const int lq   = lane >> 4;
    const int swz  = lrow & 3;

    // ---------------- one-time staging ----------------
    if (tid < 512) { int r = tid >> 7, j = tid & (HID - 1); sW1r[r][j] = W1[r * HID + j]; }
    if (tid < HID) sB1[tid] = b1[tid];
    else if (tid < 2 * HID) sB2[tid - HID] = b2[tid - HID];
    else if (tid < 3 * HID) sW3[tid - 2 * HID] = W3[tid - 2 * HID];

    #pragma unroll
    for (int tt = 0; tt < 2; ++tt) {
        int e = tid + tt * TPB;       // 0..2047 frag-line slots
        int t = e >> 6, l = e & 63;
        int a = t >> 2, bidx = t & 3; // (jt,kt) for sW2A ; (it,jt2) for sW2R
        int lr = l & 15, q = l >> 4;
        bf16x8 f;
        #pragma unroll
        for (int idx = 0; idx < 8; ++idx)
            f[idx] = (bf16)W2[(32*bidx + 8*q + idx) * HID + 16*a + lr];
        *reinterpret_cast<bf16x8*>(&sW2A[e * 8]) = f;
        const float4* rp = reinterpret_cast<const float4*>(&W2[(16*a + lr) * HID + 32*bidx + 8*q]);
        float4 r0 = rp[0], r1 = rp[1];
        bf16x8 g;
        g[0]=(bf16)r0.x; g[1]=(bf16)r0.y; g[2]=(bf16)r0.z; g[3]=(bf16)r0.w;
        g[4]=(bf16)r1.x; g[5]=(bf16)r1.y; g[6]=(bf16)r1.z; g[7]=(bf16)r1.w;
        *reinterpret_cast<bf16x8*>(&sW2R[e * 8]) = g;
    }
    if (tid < 256) { // W1 A-frag lines: A[m=lr][k=32m+8q+idx], rows>=4 zero
        int m = tid >> 6, l = tid & 63;
        int lr = l & 15, q = l >> 4;
        bf16x8 f = {};
        if (lr < 4) {
            #pragma unroll
            for (int idx = 0; idx < 8; ++idx)
                f[idx] = (bf16)W1[lr * HID + 32*m + 8*q + idx];
        }
        *reinterpret_cast<bf16x8*>(&sW1A[m][l * 8]) = f;
    }
    __syncthreads(); // ONLY barrier in the kernel

    bf16* const myX = &sXf[w][0];

    const int tileStride = GRIDB * NW;
    const int t0 = (int)blockIdx.x * NW + w;
    const floatx4 fz = floatx4{0.f,0.f,0.f,0.f};

    auto loadX = [&](int t) -> float4 {
        int gc = t * 16 + lrow; gc = gc < B ? gc : (B - 1);
        return reinterpret_cast<const float4*>(X)[gc];
    };

    float4 xc = loadX(t0);

    #pragma unroll 1
    for (int c = 0; c < nchunk; ++c) {
        const int tile = t0 + c * tileStride;
        if (tile * 16 >= B) break;              // per-wave divergence OK: no barriers
        const int S0 = tile * 16;
        float4 xn = loadX(tile + tileStride);   // clamped; garbage-safe on last iter

        float s1, c1, s2, c2;
        __sincosf(xc.x, &s1, &c1);
        __sincosf(xc.y, &s2, &c2);
        const float qd1 = xc.z, qd2 = xc.w;

        // ---- P1: feat -> H1^T B-frags in regs (breg[kt] = h1[32kt+8lq+idx][lrow]) ----
        bf16x8 breg[4];
        #pragma unroll
        for (int kt = 0; kt < 4; ++kt) {
            int jb = 32 * kt + 8 * lq;
            floatx4 w0a = *reinterpret_cast<const floatx4*>(&sW1r[0][jb]);
            floatx4 w0b = *reinterpret_cast<const floatx4*>(&sW1r[0][jb+4]);
            floatx4 w1a = *reinterpret_cast<const floatx4*>(&sW1r[1][jb]);
            floatx4 w1b = *reinterpret_cast<const floatx4*>(&sW1r[1][jb+4]);
            floatx4 w2a = *reinterpret_cast<const floatx4*>(&sW1r[2][jb]);
            floatx4 w2b = *reinterpret_cast<const floatx4*>(&sW1r[2][jb+4]);
            floatx4 w3a = *reinterpret_cast<const floatx4*>(&sW1r[3][jb]);
            floatx4 w3b = *reinterpret_cast<const floatx4*>(&sW1r[3][jb+4]);
            floatx4 bba = *reinterpret_cast<const floatx4*>(&sB1[jb]);
            floatx4 bbb = *reinterpret_cast<const floatx4*>(&sB1[jb+4]);
            floatx4 za = bba + s1*w0a + c1*w1a + s2*w2a + c2*w3a;
            floatx4 zb = bbb + s1*w0b + c1*w1b + s2*w2b + c2*w3b;
            floatx4 ha = tanh4(za);
            floatx4 hb = tanh4(zb);
            bf16x8 hf;
            hf[0]=(bf16)ha[0]; hf[1]=(bf16)ha[1]; hf[2]=(bf16)ha[2]; hf[3]=(bf16)ha[3];
            hf[4]=(bf16)hb[0]; hf[5]=(bf16)hb[1]; hf[6]=(bf16)hb[2]; hf[7]=(bf16)hb[3];
            breg[kt] = hf;
        }

        // ---- GEMM1t + Phase3a per jt (ROLLING acc, immediate transform write) ----
        #pragma unroll
        for (int jt = 0; jt < 8; ++jt) {
            floatx4 acc = __builtin_amdgcn_mfma_f32_16x16x32_bf16(
                *reinterpret_cast<const bf16x8*>(&sW2A[((jt*4 + 0)*64 + lane)*8]),
                breg[0], fz, 0,0,0);
            #pragma unroll
            for (int kt = 1; kt < 4; ++kt)
                acc = __builtin_amdgcn_mfma_f32_16x16x32_bf16(
                    *reinterpret_cast<const bf16x8*>(&sW2A[((jt*4 + kt)*64 + lane)*8]),
                    breg[kt], acc, 0,0,0);
            int jb = 16*jt + 4*lq;
            floatx4 b2v = *reinterpret_cast<const floatx4*>(&sB2[jb]);
            floatx4 w3v = *reinterpret_cast<const floatx4*>(&sW3[jb]);
            floatx4 h = tanh4(acc + b2v);
            floatx4 gv = (1.0f - h*h) * w3v;
            bf16x4 g;
            g[0]=(bf16)gv[0]; g[1]=(bf16)gv[1]; g[2]=(bf16)gv[2]; g[3]=(bf16)gv[3];
            int blk = (2*(jt&1) + (lq>>1)) ^ swz;
            *reinterpret_cast<bf16x4*>(&myX[(jt>>1)*512 + lrow*32 + blk*8 + 4*(lq&1)]) = g;
        }

        // ---- Phase 3b: batched B-line reads (single LDS round trip) ----
        bf16x8 gB[4];
        #pragma unroll
        for (int L = 0; L < 4; ++L)
            gB[L] = *reinterpret_cast<const bf16x8*>(&myX[L*512 + lrow*32 + (lq ^ swz)*8]);

        // ---- GEMM2t + Phase5a per it (ROLLING acc2, immediate transform write) ----
        #pragma unroll
        for (int it = 0; it < 8; ++it) {
            floatx4 acc2 = __builtin_amdgcn_mfma_f32_16x16x32_bf16(
                *reinterpret_cast<const bf16x8*>(&sW2R[((it*4 + 0)*64 + lane)*8]),
                gB[0], fz, 0,0,0);
            #pragma unroll
            for (int jt2 = 1; jt2 < 4; ++jt2)
                acc2 = __builtin_amdgcn_mfma_f32_16x16x32_bf16(
                    *reinterpret_cast<const bf16x8*>(&sW2R[((it*4 + jt2)*64 + lane)*8]),
                    gB[jt2], acc2, 0,0,0);
            bf16x4 g;
            g[0]=(bf16)acc2[0]; g[1]=(bf16)acc2[1];
            g[2]=(bf16)acc2[2]; g[3]=(bf16)acc2[3];
            int blk = (2*(it&1) + (lq>>1)) ^ swz;
            *reinterpret_cast<bf16x4*>(&myX[(it>>1)*512 + lrow*32 + blk*8 + 4*(lq&1)]) = g;
        }

        // ---- Phase 5b + GEMM3t: G1 = (1-h1^2)*S from breg (B-layout match) ----
        floatx4 dv = fz;
        #pragma unroll
        for (int m = 0; m < 4; ++m) {
            bf16x8 sv = *reinterpret_cast<const bf16x8*>(&myX[m*512 + lrow*32 + (lq ^ swz)*8]);
            bf16x8 g1;
            #pragma unroll
            for (int idx = 0; idx < 8; ++idx) {
                float h = (float)breg[m][idx];
                float s = (float)sv[idx];
                g1[idx] = (bf16)(s - s*h*h);
            }
            dv = __builtin_amdgcn_mfma_f32_16x16x32_bf16(
                *reinterpret_cast<const bf16x8*>(&sW1A[m][lane*8]), g1, dv, 0,0,0);
        }

        // ---- Epilogue: lanes 0..15 (lq=0) hold dv rows 0..3 for sample lrow ----
        if (lane < 16 && S0 + lane < B) {
            float dV0 = dv[0], dV1 = dv[1], dV2 = dv[2], dV3 = dv[3];
            float cosD = c1 * c2 + s1 * s2;
            float sinD = s1 * c2 - c1 * s2;
            float dVt1 = dV0 * c1 - dV1 * s1;   // dV/dt1
            float dVt2 = dV2 * c2 - dV3 * s2;   // dV/dt2
            float sT = qd1 * qd2 * sinD;        // dT/dt1 = -sT, dT/dt2 = +sT
            float cw = sinD * (qd2 - qd1);
            float rhs1 = (-sT - dVt1) - qd2 * cw;
            float rhs2 = ( sT - dVt2) - qd1 * cw;
            float det = 2.0f - cosD * cosD;     // det(M) in [1,2]
            float inv = __builtin_amdgcn_rcpf(det);
            float qdd1 = (rhs1 - cosD * rhs2) * inv;
            float qdd2 = (2.0f * rhs2 - cosD * rhs1) * inv;
            *reinterpret_cast<float4*>(&out[4 * (S0 + lane)]) = make_float4(qd1, qd2, qdd1, qdd2);
        }
        xc = xn;
    }
}

extern "C" void kernel_launch(void* const* d_in, const int* in_sizes, int n_in,
                              void* d_out, int out_size, void* d_ws, size_t ws_size,
                              hipStream_t stream) {
    const float* X  = (const float*)d_in[0];
    const float* W1 = (const float*)d_in[1];
    const float* b1 = (const float*)d_in[2];
    const float* W2 = (const float*)d_in[3];
    const float* b2 = (const float*)d_in[4];
    const float* W3 = (const float*)d_in[5];
    // d_in[6] = b3: constant offset on V, vanishes in all gradients
    float* out = (float*)d_out;
    int B = in_sizes[0] / 4;
    int tiles = (B + 15) >> 4;
    int nchunk = (tiles + GRIDB * NW - 1) / (GRIDB * NW);
    lnn_kernel<<<GRIDB, TPB, 0, stream>>>(X, W1, b1, b2, W3, W2, out, B, nchunk);
}